// Round 14
// baseline (108.672 us; speedup 1.0000x reference)
//
#include <hip/hip_runtime.h>
#include <hip/hip_bf16.h>

// ---------------------------------------------------------------------------
// CMHSAttn v12: fp32 in/out. R9-R13 elimination: attn (~33us) immune to
// load-count, load-latency, and VALU-pack deletion -> the only unperturbed
// pipe is the transcendental unit (134M v_exp_f32, invariant per-SIMD).
// v12 discriminator: exp moved to the VALU pipe via 7-instr quadratic-minimax
// exp2 (rel err 1.7e-3 << bf16 P quantization). Otherwise identical to R13.
// ---------------------------------------------------------------------------

typedef __attribute__((ext_vector_type(4))) float    f32x4;
typedef __attribute__((ext_vector_type(8))) short    s16x8;
typedef __attribute__((ext_vector_type(4))) short    s16x4;
typedef __attribute__((ext_vector_type(8))) __bf16   bf16x8;
typedef __attribute__((ext_vector_type(4))) unsigned u32x4;

union FragAB { s16x8 s; bf16x8 b; u32x4 u; };

__device__ __forceinline__ short f2bf(float f) {
    unsigned u = __float_as_uint(f);
    u += 0x7fff + ((u >> 16) & 1);          // RNE
    return (short)(u >> 16);
}

__device__ __forceinline__ unsigned pkbf(float a, float b) {
    float2 f2; f2.x = a; f2.y = b;
    __hip_bfloat162 h = __float22bfloat162_rn(f2);   // v_cvt_pk_bf16_f32
    unsigned r;
    __builtin_memcpy(&r, &h, 4);                      // lo = a, hi = b
    return r;
}

// VALU-pipe exp2: floor + sub + 2 fma (minimax quadratic, max rel err 1.7e-3)
// + cvt_i32 + lshl_add + mul. Safe for |x| < 126 (|st| <= ~75 by construction).
__device__ __forceinline__ float fexp2(float x) {
    float n = floorf(x);
    float f = x - n;
    float p = fmaf(f, 0.33718944f, 0.657636276f);
    p = fmaf(f, p, 1.00172476f);
    int e = (int)n;
    float s = __int_as_float((e + 127) << 23);
    return p * s;
}

#define QK_SCALE 0.12751744154070513f   // (1/sqrt(128)) * log2(e)

// ---------------------------------------------------------------------------
// QKV (unchanged, validated R8): MFMA GEMM; V written PV-slot-permuted:
// v2[h][d][T][c][quad][j] = V[d][ T*64 + c*32 + (j>=4?16:0) + quad*4 + (j&3) ]
// ---------------------------------------------------------------------------
__global__ __launch_bounds__(256) void qkv_kernel(
    const float* __restrict__ x, const float* __restrict__ w,
    short* __restrict__ qT, short* __restrict__ kT, short* __restrict__ v2)
{
    __shared__ __align__(16) short xT[4][16][136];   // [wave][n][c], pad 8
    const int wv   = threadIdx.x >> 6;
    const int lane = threadIdx.x & 63;
    const int colL = lane & 15, quad = lane >> 4;
    const int n0 = blockIdx.x * 64 + wv * 16;
    const int oq = blockIdx.y;                        // 0..3

    #pragma unroll
    for (int rr = 0; rr < 4; ++rr) {
        int c  = rr * 32 + (lane >> 1);
        int nh = (lane & 1) * 8;
        f32x4 a = *(const f32x4*)&x[c * 4096 + n0 + nh];
        f32x4 b = *(const f32x4*)&x[c * 4096 + n0 + nh + 4];
        #pragma unroll
        for (int t = 0; t < 4; ++t) {
            xT[wv][nh + t][c]     = f2bf(a[t]);
            xT[wv][nh + 4 + t][c] = f2bf(b[t]);
        }
    }
    __syncthreads();

    FragAB xb[4];
    #pragma unroll
    for (int ks = 0; ks < 4; ++ks)
        xb[ks].s = *(const s16x8*)&xT[wv][colL][ks * 32 + quad * 8];

    const int T    = blockIdx.x;
    const int wloc = wv * 16 + colL;          // n & 63
    const int cc   = wloc >> 5;
    const int bb   = (wloc >> 4) & 1;
    const int qp   = (wloc >> 2) & 3;
    const int jj   = bb * 4 + (wloc & 3);
    const int vslot = ((T * 2 + cc) * 4 + qp) * 8 + jj;

    #pragma unroll
    for (int i = 0; i < 6; ++i) {
        const int otg  = oq * 6 + i;
        const int ob   = otg * 16;
        const int h    = otg / 3;
        const int kind = otg % 3;             // 0=q, 1=k, 2=v
        f32x4 acc = {0.f, 0.f, 0.f, 0.f};
        #pragma unroll
        for (int ks = 0; ks < 4; ++ks) {
            f32x4 wa0 = *(const f32x4*)&w[(ob + colL) * 128 + ks * 32 + quad * 8];
            f32x4 wa1 = *(const f32x4*)&w[(ob + colL) * 128 + ks * 32 + quad * 8 + 4];
            FragAB wa;
            #pragma unroll
            for (int t = 0; t < 4; ++t) {
                wa.s[t]     = f2bf(wa0[t]);
                wa.s[t + 4] = f2bf(wa1[t]);
            }
            acc = __builtin_amdgcn_mfma_f32_16x16x32_bf16(wa.b, xb[ks].b, acc, 0, 0, 0);
        }
        if (kind == 2) {
            #pragma unroll
            for (int r = 0; r < 4; ++r) {
                int d = quad * 4 + r;
                v2[(h * 16 + d) * 4096 + vslot] = f2bf(acc[r]);
            }
        } else {
            short* dst = (kind == 0) ? qT : kT;
            const float sc = (kind == 0) ? QK_SCALE : 1.0f;
            s16x4 pk;
            #pragma unroll
            for (int r = 0; r < 4; ++r) pk[r] = f2bf(acc[r] * sc);
            *(s16x4*)&dst[(h * 4096 + n0 + colL) * 16 + quad * 4] = pk;
        }
    }
}

// ---------------------------------------------------------------------------
// Attention v12: wave = 64 q (four 16-q tiles) x key chunk. SPLIT=8.
// Per pair: 4 QK MFMA -> 16 VALU-exp2 -> 8 cvt_pk -> 2 PV MFMA + 2 l-MFMA.
// l[q] = ol[u][0] at loop end (every C row of ones*P^T is the column sum).
// ---------------------------------------------------------------------------
template<int SPLIT>
__global__ __launch_bounds__(256) void attn_kernel(
    const short* __restrict__ qT, const short* __restrict__ kT,
    const short* __restrict__ v2,
    float* __restrict__ Opart, float* __restrict__ lpart,
    float* __restrict__ out)
{
    const int wv   = threadIdx.x >> 6;
    const int lane = threadIdx.x & 63;
    const int colL = lane & 15, quad = lane >> 4;

    const int bx = blockIdx.x;
    int s, h, b;
    if (SPLIT > 1) { s = bx >> 7; h = (bx >> 4) & 7; b = bx & 15; }
    else           { s = 0;       h = bx >> 4;       b = bx & 15; }
    const int qbase = b * 256 + wv * 64;     // this wave's 64 q rows
    const int nkt = 64 / SPLIT;

    const short* kb  = kT +  h * 4096 * 16;
    const short* vb2 = v2 + (h * 16 + colL) * 4096;

    FragAB qfs[4];                            // B-frags: Q^T[d][q], d<16
    #pragma unroll
    for (int u = 0; u < 4; ++u) {
        qfs[u].s = 0;
        if (quad < 2)
            qfs[u].s = *(const s16x8*)&qT[(h * 4096 + qbase + u * 16 + colL) * 16 + quad * 8];
    }

    FragAB ones;                              // all-ones bf16 A-frag
    #pragma unroll
    for (int j = 0; j < 8; ++j) ones.s[j] = (short)0x3F80;

    f32x4 o[4], ol[4];
    #pragma unroll
    for (int u = 0; u < 4; ++u) {
        o[u]  = (f32x4){0.f, 0.f, 0.f, 0.f};
        ol[u] = (f32x4){0.f, 0.f, 0.f, 0.f};
    }

    const int kt_base = s * nkt;
    for (int kt = 0; kt < nkt; ++kt) {
        const int T  = kt_base + kt;
        const int m0 = T * 64;

        s16x8 kfr[4];
        #pragma unroll
        for (int t = 0; t < 4; ++t)
            kfr[t] = *(const s16x8*)&kb[(m0 + t * 16 + colL) * 16 + quad * 8];
        s16x8 vfr[2];
        #pragma unroll
        for (int c = 0; c < 2; ++c)
            vfr[c] = *(const s16x8*)&vb2[(T * 2 + c) * 32 + quad * 8];

        #pragma unroll
        for (int u = 0; u < 4; ++u) {
            f32x4 st[4];
            #pragma unroll
            for (int t = 0; t < 4; ++t) {
                FragAB kx; kx.s = kfr[t];
                f32x4 z = {0.f, 0.f, 0.f, 0.f};
                st[t] = __builtin_amdgcn_mfma_f32_16x16x32_bf16(kx.b, qfs[u].b, z, 0, 0, 0);
            }
            unsigned pk[8];
            #pragma unroll
            for (int t = 0; t < 4; ++t) {
                float p0 = fexp2(st[t][0]);
                float p1 = fexp2(st[t][1]);
                float p2 = fexp2(st[t][2]);
                float p3 = fexp2(st[t][3]);
                pk[t * 2 + 0] = pkbf(p0, p1);
                pk[t * 2 + 1] = pkbf(p2, p3);
            }
            #pragma unroll
            for (int c = 0; c < 2; ++c) {
                FragAB vf, pb;
                vf.s = vfr[c];
                pb.u = (u32x4){pk[4 * c + 0], pk[4 * c + 1], pk[4 * c + 2], pk[4 * c + 3]};
                o[u]  = __builtin_amdgcn_mfma_f32_16x16x32_bf16(vf.b,   pb.b, o[u],  0, 0, 0);
                ol[u] = __builtin_amdgcn_mfma_f32_16x16x32_bf16(ones.b, pb.b, ol[u], 0, 0, 0);
            }
        }
    }

    #pragma unroll
    for (int u = 0; u < 4; ++u) {
        const float l = ol[u][0];            // every C row = column sum = l(q)
        const int q0 = qbase + u * 16;
        if (SPLIT > 1) {
            #pragma unroll
            for (int r = 0; r < 4; ++r)
                Opart[((s * 8 + h) * 16 + quad * 4 + r) * 4096 + q0 + colL] = o[u][r];
            if (quad == 0) lpart[(s * 8 + h) * 4096 + q0 + colL] = l;
        } else {
            const float inv = 1.f / l;
            #pragma unroll
            for (int r = 0; r < 4; ++r)
                out[(h * 16 + quad * 4 + r) * 4096 + q0 + colL] = o[u][r] * inv;
        }
    }
}

// ---------------------------------------------------------------------------
template<int SPLIT>
__global__ __launch_bounds__(256) void combine_kernel(
    const float* __restrict__ Opart, const float* __restrict__ lpart,
    float* __restrict__ out)
{
    const int row = blockIdx.x >> 2;                       // 0..127 = h*16+d
    const int n   = (blockIdx.x & 3) * 1024 + threadIdx.x * 4;
    const int h   = row >> 4;
    f32x4 osum = {0.f, 0.f, 0.f, 0.f}, lsum = {0.f, 0.f, 0.f, 0.f};
    #pragma unroll
    for (int s = 0; s < SPLIT; ++s) {
        osum += *(const f32x4*)&Opart[(s * 128 + row) * 4096 + n];
        lsum += *(const f32x4*)&lpart[(s * 8 + h) * 4096 + n];
    }
    f32x4 res;
    #pragma unroll
    for (int r = 0; r < 4; ++r) res[r] = osum[r] / lsum[r];
    *(f32x4*)&out[row * 4096 + n] = res;
}

// ---------------------------------------------------------------------------
extern "C" void kernel_launch(void* const* d_in, const int* in_sizes, int n_in,
                              void* d_out, int out_size, void* d_ws, size_t ws_size,
                              hipStream_t stream) {
    const float* x = (const float*)d_in[0];   // (128, 4096) fp32
    const float* w = (const float*)d_in[1];   // (384, 128) fp32
    float* out = (float*)d_out;               // (128, 4096) fp32

    char* ws = (char*)d_ws;
    short* qT = (short*)ws;                          // 1 MB
    short* kT = (short*)(ws + (1u << 20));           // 1 MB
    short* vv = (short*)(ws + (2u << 20));           // 1 MB (permuted v2)

    constexpr int SPLIT = 8;
    const size_t opart_bytes = (size_t)SPLIT * 128 * 4096 * 4;   // 16 MB
    const size_t lpart_bytes = (size_t)SPLIT * 8 * 4096 * 4;     // 1 MB
    const size_t need_split  = (3ull << 20) + opart_bytes + lpart_bytes;

    dim3 gq(64, 4);
    qkv_kernel<<<gq, 256, 0, stream>>>(x, w, qT, kT, vv);

    if (ws_size >= need_split) {
        float* Opart = (float*)(ws + (3ull << 20));
        float* lpart = (float*)(ws + (3ull << 20) + opart_bytes);
        attn_kernel<SPLIT><<<SPLIT * 128, 256, 0, stream>>>(qT, kT, vv, Opart, lpart, out);
        combine_kernel<SPLIT><<<512, 256, 0, stream>>>(Opart, lpart, out);
    } else {
        attn_kernel<1><<<128, 256, 0, stream>>>(qT, kT, vv, nullptr, nullptr, out);
    }
}

// Round 15
// 96.747 us; speedup vs baseline: 1.1233x; 1.1233x over previous
//
#include <hip/hip_runtime.h>
#include <hip/hip_bf16.h>

// ---------------------------------------------------------------------------
// CMHSAttn v13: fp32 in/out. R14 calibration: attn is total-issue-bound with
// ~146 overhead-VALU/pair (frag copies + 64-bit addressing). v13 deletes it:
//  - interleaved kv[h][T] tile buffer (K 2KB | V-permuted 2KB): per-kt loads
//    = SGPR base advance + 2 invariant voffsets + imm offsets (0 VALU)
//  - loads land directly in FragAB unions (no copies)
//  - pb built in place; kt loop fully unrolled
// exp back on trans pipe (R14 proved VALU-exp worse). Math identical to R13.
// ---------------------------------------------------------------------------

typedef __attribute__((ext_vector_type(4))) float    f32x4;
typedef __attribute__((ext_vector_type(8))) short    s16x8;
typedef __attribute__((ext_vector_type(4))) short    s16x4;
typedef __attribute__((ext_vector_type(8))) __bf16   bf16x8;
typedef __attribute__((ext_vector_type(4))) unsigned u32x4;

union FragAB { s16x8 s; bf16x8 b; u32x4 u; };

__device__ __forceinline__ short f2bf(float f) {
    unsigned u = __float_as_uint(f);
    u += 0x7fff + ((u >> 16) & 1);          // RNE
    return (short)(u >> 16);
}

__device__ __forceinline__ unsigned pkbf(float a, float b) {
    float2 f2; f2.x = a; f2.y = b;
    __hip_bfloat162 h = __float22bfloat162_rn(f2);   // v_cvt_pk_bf16_f32
    unsigned r;
    __builtin_memcpy(&r, &h, 4);                      // lo = a, hi = b
    return r;
}

#if __has_builtin(__builtin_amdgcn_exp2f)
  #define FASTEXP(x) __builtin_amdgcn_exp2f(x)
  #define QK_SCALE 0.12751744154070513f   // (1/sqrt(128)) * log2(e)
#else
  #define FASTEXP(x) __expf(x)
  #define QK_SCALE 0.08838834764831845f   // 1/sqrt(128)
#endif

// ---------------------------------------------------------------------------
// QKV: MFMA GEMM. Q -> qT[h][n][16] (scaled). K,V -> interleaved kv buffer:
// kv[(h*64+T)*2048 + key_local*16 + d]                  (K region, 2KB/tile)
// kv[(h*64+T)*2048 + 1024 + d*64 + c*32 + qp*8 + jj]    (V region, permuted:
//   key = T*64 + c*32 + (jj>=4?16:0) + qp*4 + (jj&3) -- PV B-frag slot order)
// ---------------------------------------------------------------------------
__global__ __launch_bounds__(256) void qkv_kernel(
    const float* __restrict__ x, const float* __restrict__ w,
    short* __restrict__ qT, short* __restrict__ kv)
{
    __shared__ __align__(16) short xT[4][16][136];   // [wave][n][c], pad 8
    const int wv   = threadIdx.x >> 6;
    const int lane = threadIdx.x & 63;
    const int colL = lane & 15, quad = lane >> 4;
    const int n0 = blockIdx.x * 64 + wv * 16;
    const int oq = blockIdx.y;                        // 0..3

    #pragma unroll
    for (int rr = 0; rr < 4; ++rr) {
        int c  = rr * 32 + (lane >> 1);
        int nh = (lane & 1) * 8;
        f32x4 a = *(const f32x4*)&x[c * 4096 + n0 + nh];
        f32x4 b = *(const f32x4*)&x[c * 4096 + n0 + nh + 4];
        #pragma unroll
        for (int t = 0; t < 4; ++t) {
            xT[wv][nh + t][c]     = f2bf(a[t]);
            xT[wv][nh + 4 + t][c] = f2bf(b[t]);
        }
    }
    __syncthreads();

    FragAB xb[4];
    #pragma unroll
    for (int ks = 0; ks < 4; ++ks)
        xb[ks].s = *(const s16x8*)&xT[wv][colL][ks * 32 + quad * 8];

    const int T    = blockIdx.x;
    const int wloc = wv * 16 + colL;          // key_local = n & 63
    const int cc   = wloc >> 5;
    const int bb   = (wloc >> 4) & 1;
    const int qp   = (wloc >> 2) & 3;
    const int jj   = bb * 4 + (wloc & 3);

    #pragma unroll
    for (int i = 0; i < 6; ++i) {
        const int otg  = oq * 6 + i;
        const int ob   = otg * 16;
        const int h    = otg / 3;
        const int kind = otg % 3;             // 0=q, 1=k, 2=v
        f32x4 acc = {0.f, 0.f, 0.f, 0.f};
        #pragma unroll
        for (int ks = 0; ks < 4; ++ks) {
            f32x4 wa0 = *(const f32x4*)&w[(ob + colL) * 128 + ks * 32 + quad * 8];
            f32x4 wa1 = *(const f32x4*)&w[(ob + colL) * 128 + ks * 32 + quad * 8 + 4];
            FragAB wa;
            #pragma unroll
            for (int t = 0; t < 4; ++t) {
                wa.s[t]     = f2bf(wa0[t]);
                wa.s[t + 4] = f2bf(wa1[t]);
            }
            acc = __builtin_amdgcn_mfma_f32_16x16x32_bf16(wa.b, xb[ks].b, acc, 0, 0, 0);
        }
        // C: row = o_local = quad*4+r, col = n
        if (kind == 0) {
            s16x4 pk;
            #pragma unroll
            for (int r = 0; r < 4; ++r) pk[r] = f2bf(acc[r] * QK_SCALE);
            *(s16x4*)&qT[(h * 4096 + n0 + colL) * 16 + quad * 4] = pk;
        } else if (kind == 1) {
            s16x4 pk;
            #pragma unroll
            for (int r = 0; r < 4; ++r) pk[r] = f2bf(acc[r]);
            *(s16x4*)&kv[(h * 64 + T) * 2048 + wloc * 16 + quad * 4] = pk;
        } else {
            #pragma unroll
            for (int r = 0; r < 4; ++r) {
                int d = quad * 4 + r;
                kv[(h * 64 + T) * 2048 + 1024 + d * 64 + cc * 32 + qp * 8 + jj] = f2bf(acc[r]);
            }
        }
    }
}

// ---------------------------------------------------------------------------
// Attention v13: wave = 64 q (four 16-q tiles) x key chunk. SPLIT=8, nkt=8.
// Per kt: base advance (SALU) + 6 imm-offset loads into FragAB; per pair:
// 4 QK MFMA -> 16 trans exp -> 8 cvt_pk -> 2 PV + 2 l MFMA.
// ---------------------------------------------------------------------------
template<int SPLIT>
__global__ __launch_bounds__(256) void attn_kernel(
    const short* __restrict__ qT, const short* __restrict__ kv,
    float* __restrict__ Opart, float* __restrict__ lpart,
    float* __restrict__ out)
{
    const int wv   = threadIdx.x >> 6;
    const int lane = threadIdx.x & 63;
    const int colL = lane & 15, quad = lane >> 4;

    const int bx = blockIdx.x;
    int s, h, b;
    if (SPLIT > 1) { s = bx >> 7; h = (bx >> 4) & 7; b = bx & 15; }
    else           { s = 0;       h = bx >> 4;       b = bx & 15; }
    const int qbase = b * 256 + wv * 64;     // this wave's 64 q rows
    const int nkt = 64 / SPLIT;

    FragAB qfs[4];                            // B-frags: Q^T[d][q], d<16
    #pragma unroll
    for (int u = 0; u < 4; ++u) {
        qfs[u].s = 0;
        if (quad < 2)
            qfs[u].s = *(const s16x8*)&qT[(h * 4096 + qbase + u * 16 + colL) * 16 + quad * 8];
    }

    FragAB ones;                              // all-ones bf16 A-frag
    #pragma unroll
    for (int j = 0; j < 8; ++j) ones.s[j] = (short)0x3F80;

    f32x4 o[4], ol[4];
    #pragma unroll
    for (int u = 0; u < 4; ++u) {
        o[u]  = (f32x4){0.f, 0.f, 0.f, 0.f};
        ol[u] = (f32x4){0.f, 0.f, 0.f, 0.f};
    }

    // loop-invariant lane offsets (shorts)
    const int voffK = colL * 16 + quad * 8;          // + t*256
    const int voffV = 1024 + colL * 64 + quad * 8;   // + c*32

    const short* kvb = kv + (h * 64 + s * nkt) * 2048;

    #pragma unroll
    for (int kt = 0; kt < nkt; ++kt) {
        FragAB kf[4], vf[2];
        #pragma unroll
        for (int t = 0; t < 4; ++t)
            kf[t].s = *(const s16x8*)&kvb[voffK + t * 256];
        #pragma unroll
        for (int c = 0; c < 2; ++c)
            vf[c].s = *(const s16x8*)&kvb[voffV + c * 32];
        kvb += 2048;

        #pragma unroll
        for (int u = 0; u < 4; ++u) {
            f32x4 st[4];
            #pragma unroll
            for (int t = 0; t < 4; ++t) {
                f32x4 z = {0.f, 0.f, 0.f, 0.f};
                st[t] = __builtin_amdgcn_mfma_f32_16x16x32_bf16(kf[t].b, qfs[u].b, z, 0, 0, 0);
            }
            FragAB p0, p1;
            #pragma unroll
            for (int t = 0; t < 2; ++t) {
                p0.u[t * 2 + 0] = pkbf(FASTEXP(st[t][0]), FASTEXP(st[t][1]));
                p0.u[t * 2 + 1] = pkbf(FASTEXP(st[t][2]), FASTEXP(st[t][3]));
                p1.u[t * 2 + 0] = pkbf(FASTEXP(st[t + 2][0]), FASTEXP(st[t + 2][1]));
                p1.u[t * 2 + 1] = pkbf(FASTEXP(st[t + 2][2]), FASTEXP(st[t + 2][3]));
            }
            o[u]  = __builtin_amdgcn_mfma_f32_16x16x32_bf16(vf[0].b, p0.b, o[u],  0, 0, 0);
            ol[u] = __builtin_amdgcn_mfma_f32_16x16x32_bf16(ones.b,  p0.b, ol[u], 0, 0, 0);
            o[u]  = __builtin_amdgcn_mfma_f32_16x16x32_bf16(vf[1].b, p1.b, o[u],  0, 0, 0);
            ol[u] = __builtin_amdgcn_mfma_f32_16x16x32_bf16(ones.b,  p1.b, ol[u], 0, 0, 0);
        }
    }

    #pragma unroll
    for (int u = 0; u < 4; ++u) {
        const float l = ol[u][0];            // every C row = column sum = l(q)
        const int q0 = qbase + u * 16;
        if (SPLIT > 1) {
            #pragma unroll
            for (int r = 0; r < 4; ++r)
                Opart[((s * 8 + h) * 16 + quad * 4 + r) * 4096 + q0 + colL] = o[u][r];
            if (quad == 0) lpart[(s * 8 + h) * 4096 + q0 + colL] = l;
        } else {
            const float inv = 1.f / l;
            #pragma unroll
            for (int r = 0; r < 4; ++r)
                out[(h * 16 + quad * 4 + r) * 4096 + q0 + colL] = o[u][r] * inv;
        }
    }
}

// ---------------------------------------------------------------------------
template<int SPLIT>
__global__ __launch_bounds__(256) void combine_kernel(
    const float* __restrict__ Opart, const float* __restrict__ lpart,
    float* __restrict__ out)
{
    const int row = blockIdx.x >> 2;                       // 0..127 = h*16+d
    const int n   = (blockIdx.x & 3) * 1024 + threadIdx.x * 4;
    const int h   = row >> 4;
    f32x4 osum = {0.f, 0.f, 0.f, 0.f}, lsum = {0.f, 0.f, 0.f, 0.f};
    #pragma unroll
    for (int s = 0; s < SPLIT; ++s) {
        osum += *(const f32x4*)&Opart[(s * 128 + row) * 4096 + n];
        lsum += *(const f32x4*)&lpart[(s * 8 + h) * 4096 + n];
    }
    f32x4 res;
    #pragma unroll
    for (int r = 0; r < 4; ++r) res[r] = osum[r] / lsum[r];
    *(f32x4*)&out[row * 4096 + n] = res;
}

// ---------------------------------------------------------------------------
extern "C" void kernel_launch(void* const* d_in, const int* in_sizes, int n_in,
                              void* d_out, int out_size, void* d_ws, size_t ws_size,
                              hipStream_t stream) {
    const float* x = (const float*)d_in[0];   // (128, 4096) fp32
    const float* w = (const float*)d_in[1];   // (384, 128) fp32
    float* out = (float*)d_out;               // (128, 4096) fp32

    char* ws = (char*)d_ws;
    short* qT = (short*)ws;                          // 1 MB
    short* kv = (short*)(ws + (1u << 20));           // 2 MB interleaved K|V

    constexpr int SPLIT = 8;
    const size_t opart_bytes = (size_t)SPLIT * 128 * 4096 * 4;   // 16 MB
    const size_t lpart_bytes = (size_t)SPLIT * 8 * 4096 * 4;     // 1 MB
    const size_t need_split  = (3ull << 20) + opart_bytes + lpart_bytes;

    dim3 gq(64, 4);
    qkv_kernel<<<gq, 256, 0, stream>>>(x, w, qT, kv);

    if (ws_size >= need_split) {
        float* Opart = (float*)(ws + (3ull << 20));
        float* lpart = (float*)(ws + (3ull << 20) + opart_bytes);
        attn_kernel<SPLIT><<<SPLIT * 128, 256, 0, stream>>>(qT, kv, Opart, lpart, out);
        combine_kernel<SPLIT><<<512, 256, 0, stream>>>(Opart, lpart, out);
    } else {
        attn_kernel<1><<<128, 256, 0, stream>>>(qT, kv, nullptr, nullptr, out);
    }
}